// Round 1
// baseline (577.962 us; speedup 1.0000x reference)
//
#include <hip/hip_runtime.h>
#include <math.h>

#define NROWS 65536
#define NCODES 1024
#define DIM 256
#define BM 128
#define CC_CHUNK 128
#define K_CHUNK 64
#define FLAG_CAP 4096

struct Cand { int row; int i1; int i2; };

// ---------------- Kernel 0: codebook squared norms ----------------
__global__ void vq_esq_kernel(const float* __restrict__ cb, float* __restrict__ esq) {
    int c = blockIdx.x * blockDim.x + threadIdx.x;
    if (c >= NCODES) return;
    const float4* row = reinterpret_cast<const float4*>(cb + (size_t)c * DIM);
    float s = 0.f;
#pragma unroll
    for (int i = 0; i < DIM / 4; ++i) {
        float4 v = row[i];
        s += v.x * v.x + v.y * v.y + v.z * v.z + v.w * v.w;
    }
    esq[c] = s;
}

// ---------------- Kernel 1: fused distances + per-row argmin (top-2) ----------------
// Block: 128 rows x all 1024 codes. Per-thread 8x8 register tile.
// score(c) = e_sq[c] - 2*z.e  (z_sq dropped: constant per row)
__global__ __launch_bounds__(256, 2)
void vq_argmin_kernel(const float* __restrict__ z, const float* __restrict__ cb,
                      const float* __restrict__ esq, int* __restrict__ idx_out,
                      int* __restrict__ flag_count, Cand* __restrict__ flags) {
    __shared__ float zL[K_CHUNK][BM];        // 32 KB, transposed [d][row]
    __shared__ float cL[K_CHUNK][CC_CHUNK];  // 32 KB, transposed [d][code]

    const int tid = threadIdx.x;
    const int tx = tid & 15;   // code-group
    const int ty = tid >> 4;   // row-group
    const int b0 = blockIdx.x * BM;

    float bestv[8], secv[8];
    int besti[8], seci[8];
#pragma unroll
    for (int i = 0; i < 8; ++i) { bestv[i] = INFINITY; secv[i] = INFINITY; besti[i] = 0; seci[i] = 0; }

    const int sr = tid >> 4;          // staging sub-row 0..15
    const int sd0 = (tid & 15) * 4;   // staging dim 0..60 (x4)
    const int ssw = ((sd0 >> 2) & 3) << 3;  // XOR swizzle for this d-quad

    for (int cc = 0; cc < NCODES / CC_CHUNK; ++cc) {
        float acc[8][8];
#pragma unroll
        for (int i = 0; i < 8; ++i)
#pragma unroll
            for (int j = 0; j < 8; ++j) acc[i][j] = 0.f;

        for (int kc = 0; kc < DIM / K_CHUNK; ++kc) {
            __syncthreads();
            // stage z tile (transpose into LDS, swizzled column)
#pragma unroll
            for (int p = 0; p < 8; ++p) {
                int row = sr + p * 16;
                float4 v = *reinterpret_cast<const float4*>(
                    &z[(size_t)(b0 + row) * DIM + kc * K_CHUNK + sd0]);
                int col = row ^ ssw;
                zL[sd0 + 0][col] = v.x;
                zL[sd0 + 1][col] = v.y;
                zL[sd0 + 2][col] = v.z;
                zL[sd0 + 3][col] = v.w;
            }
            // stage codebook tile
#pragma unroll
            for (int p = 0; p < 8; ++p) {
                int c = sr + p * 16;
                float4 v = *reinterpret_cast<const float4*>(
                    &cb[(size_t)(cc * CC_CHUNK + c) * DIM + kc * K_CHUNK + sd0]);
                int col = c ^ ssw;
                cL[sd0 + 0][col] = v.x;
                cL[sd0 + 1][col] = v.y;
                cL[sd0 + 2][col] = v.z;
                cL[sd0 + 3][col] = v.w;
            }
            __syncthreads();

#pragma unroll 8
            for (int d = 0; d < K_CHUNK; ++d) {
                int sw = ((d >> 2) & 3) << 3;
                int zc = (ty * 8) ^ sw;
                int ccol = (tx * 8) ^ sw;
                float4 za = *reinterpret_cast<const float4*>(&zL[d][zc]);
                float4 zb = *reinterpret_cast<const float4*>(&zL[d][zc + 4]);
                float4 ca = *reinterpret_cast<const float4*>(&cL[d][ccol]);
                float4 cb4 = *reinterpret_cast<const float4*>(&cL[d][ccol + 4]);
                float zr[8] = {za.x, za.y, za.z, za.w, zb.x, zb.y, zb.z, zb.w};
                float cr[8] = {ca.x, ca.y, ca.z, ca.w, cb4.x, cb4.y, cb4.z, cb4.w};
#pragma unroll
                for (int i = 0; i < 8; ++i)
#pragma unroll
                    for (int j = 0; j < 8; ++j)
                        acc[i][j] = fmaf(zr[i], cr[j], acc[i][j]);
            }
        }
        // epilogue: update per-row top-2 over this chunk's codes (ascending idx)
#pragma unroll
        for (int j = 0; j < 8; ++j) {
            int c = cc * CC_CHUNK + tx * 8 + j;
            float es = esq[c];
#pragma unroll
            for (int i = 0; i < 8; ++i) {
                float dist = fmaf(-2.f, acc[i][j], es);
                if (dist < bestv[i]) {
                    secv[i] = bestv[i]; seci[i] = besti[i];
                    bestv[i] = dist; besti[i] = c;
                } else if (dist < secv[i]) {
                    secv[i] = dist; seci[i] = c;
                }
            }
        }
    }

    // cross-thread (tx) top-2 reduce via LDS
    __syncthreads();
    float* red = &cL[0][0];
    int* redi = reinterpret_cast<int*>(red);
#pragma unroll
    for (int i = 0; i < 8; ++i) {
        int row = ty * 8 + i;
        int base = row * 64 + tx * 4;
        red[base + 0] = bestv[i];
        redi[base + 1] = besti[i];
        red[base + 2] = secv[i];
        redi[base + 3] = seci[i];
    }
    __syncthreads();
    if (tid < BM) {
        int row = tid;
        float bv = INFINITY, sv = INFINITY;
        int bi = 0, si = 0;
        for (int t = 0; t < 16; ++t) {
            int base = row * 64 + t * 4;
            float v = red[base + 0];
            int ix = redi[base + 1];
            float v2 = red[base + 2];
            int ix2 = redi[base + 3];
            if (v < bv || (v == bv && ix < bi)) {
                float ov = bv; int oi = bi;
                bv = v; bi = ix;
                if (ov < v2 || (ov == v2 && oi < ix2)) { sv = ov; si = oi; }
                else { sv = v2; si = ix2; }
            } else {
                if (v < sv || (v == sv && ix < si)) { sv = v; si = ix; }
            }
        }
        idx_out[b0 + row] = bi;
        // near-tie: refine in fp64 later
        if (sv - bv < 1e-6f) {
            int pos = atomicAdd(flag_count, 1);
            if (pos < FLAG_CAP) { flags[pos].row = b0 + row; flags[pos].i1 = bi; flags[pos].i2 = si; }
        }
    }
}

// ---------------- Kernel 1b: fp64 rescoring of near-tie rows ----------------
__global__ void vq_fallback_kernel(const float* __restrict__ z, const float* __restrict__ cb,
                                   const int* __restrict__ flag_count,
                                   const Cand* __restrict__ flags, int* __restrict__ idx_out) {
    int n = *flag_count;
    if (n > FLAG_CAP) n = FLAG_CAP;
    for (int t = threadIdx.x + blockIdx.x * blockDim.x; t < n; t += blockDim.x * gridDim.x) {
        Cand f = flags[t];
        const float* zp = z + (size_t)f.row * DIM;
        const float* e1 = cb + (size_t)f.i1 * DIM;
        const float* e2 = cb + (size_t)f.i2 * DIM;
        double d1 = 0.0, d2 = 0.0;
        for (int d = 0; d < DIM; ++d) {
            double zd = (double)zp[d];
            double a = (double)e1[d];
            double b = (double)e2[d];
            d1 += a * (a - 2.0 * zd);
            d2 += b * (b - 2.0 * zd);
        }
        int win = (d2 < d1 || (d2 == d1 && f.i2 < f.i1)) ? f.i2 : f.i1;
        idx_out[f.row] = win;
    }
}

// ---------------- Kernel 2: gather z_q, write out0, loss partials, histogram ----------------
__global__ __launch_bounds__(256)
void vq_out_kernel(const float* __restrict__ z, const float* __restrict__ cb,
                   const int* __restrict__ idx, float* __restrict__ out,
                   float* __restrict__ loss_sum, int* __restrict__ hist) {
    const int tid = threadIdx.x;
    const int b0 = blockIdx.x * 64;
    const int rl = tid >> 6;
    const int d4 = (tid & 63) * 4;
    float acc = 0.f;
#pragma unroll 4
    for (int p = 0; p < 16; ++p) {
        int row = b0 + p * 4 + rl;
        int ci = idx[row];
        float4 zv = *reinterpret_cast<const float4*>(&z[(size_t)row * DIM + d4]);
        float4 qv = *reinterpret_cast<const float4*>(&cb[(size_t)ci * DIM + d4]);
        float dx = qv.x - zv.x, dy = qv.y - zv.y, dzz = qv.z - zv.z, dw = qv.w - zv.w;
        float4 o;
        o.x = zv.x + dx; o.y = zv.y + dy; o.z = zv.z + dzz; o.w = zv.w + dw;  // z + (z_q - z)
        *reinterpret_cast<float4*>(&out[(size_t)row * DIM + d4]) = o;
        acc += dx * dx + dy * dy + dzz * dzz + dw * dw;
    }
#pragma unroll
    for (int off = 32; off > 0; off >>= 1) acc += __shfl_down(acc, off, 64);
    __shared__ float wsum[4];
    if ((tid & 63) == 0) wsum[tid >> 6] = acc;
    __syncthreads();
    if (tid == 0) atomicAdd(loss_sum, wsum[0] + wsum[1] + wsum[2] + wsum[3]);
    if (tid < 64) atomicAdd(&hist[idx[b0 + tid]], 1);
}

// ---------------- Kernel 3: perplexity + vq_loss ----------------
__global__ __launch_bounds__(256)
void vq_final_kernel(const int* __restrict__ hist, const float* __restrict__ loss_sum,
                     float* __restrict__ out) {
    int tid = threadIdx.x;
    float s = 0.f;
    for (int t = tid; t < NCODES; t += 256) {
        float p = (float)hist[t] * (1.0f / 65536.f);
        s += p * logf(p + 1e-10f);
    }
#pragma unroll
    for (int off = 32; off > 0; off >>= 1) s += __shfl_down(s, off, 64);
    __shared__ float wsum[4];
    if ((tid & 63) == 0) wsum[tid >> 6] = s;
    __syncthreads();
    if (tid == 0) {
        float tot = wsum[0] + wsum[1] + wsum[2] + wsum[3];
        float perp = expf(-tot);
        float mse = loss_sum[0] * (1.0f / 16777216.f);
        float ratio = 102.4f / (perp + 1e-10f);
        ratio = fminf(fmaxf(ratio, 0.f), 10.f);
        // loss_codebook == loss_commit numerically -> 1.25*mse
        out[(size_t)NROWS * DIM] = 1.25f * mse + 0.1f * ratio;
        out[(size_t)NROWS * DIM + 1] = perp;
    }
}

extern "C" void kernel_launch(void* const* d_in, const int* in_sizes, int n_in,
                              void* d_out, int out_size, void* d_ws, size_t ws_size,
                              hipStream_t stream) {
    const float* z = (const float*)d_in[0];
    const float* cb = (const float*)d_in[1];
    float* out = (float*)d_out;
    char* ws = (char*)d_ws;

    // workspace layout
    int*   idx   = (int*)(ws + 0);           // 65536 * 4 = 262144 B
    int*   hist  = (int*)(ws + 262144);      // 4096 B
    float* loss  = (float*)(ws + 266240);    // 4 B
    int*   cnt   = (int*)(ws + 266244);      // 4 B
    float* esq   = (float*)(ws + 270336);    // 4096 B
    Cand*  flags = (Cand*)(ws + 274432);     // 49152 B

    hipMemsetAsync(ws + 262144, 0, 4104, stream);  // hist + loss + cnt
    vq_esq_kernel<<<4, 256, 0, stream>>>(cb, esq);
    vq_argmin_kernel<<<NROWS / BM, 256, 0, stream>>>(z, cb, esq, idx, cnt, flags);
    vq_fallback_kernel<<<8, 256, 0, stream>>>(z, cb, cnt, flags, idx);
    vq_out_kernel<<<NROWS / 64, 256, 0, stream>>>(z, cb, idx, out, loss, hist);
    vq_final_kernel<<<1, 256, 0, stream>>>(hist, loss, out);
}

// Round 4
// 266.151 us; speedup vs baseline: 2.1716x; 2.1716x over previous
//
#include <hip/hip_runtime.h>
#include <math.h>

#define NROWS 65536
#define NCODES 1024
#define DIM 256
#define BM 64            // z-rows per block
#define CCH 256          // codes per cc chunk
#define NCC 4            // NCODES / CCH
#define BK 64            // k per staging step
#define NKC 4            // DIM / BK
#define FLAG_CAP 8192
#define FLAG_GAP 3e-4f

typedef _Float16 h8 __attribute__((ext_vector_type(8)));
typedef _Float16 h4 __attribute__((ext_vector_type(4)));
typedef float f32x4 __attribute__((ext_vector_type(4)));

struct Flag { int row; int i1; int i2; };

__device__ __forceinline__ void gl_lds16(void* lds, const void* g) {
    __builtin_amdgcn_global_load_lds(
        (const __attribute__((address_space(1))) unsigned int*)g,
        (__attribute__((address_space(3))) unsigned int*)lds, 16, 0, 0);
}

// ---------- prep_z: z fp32 -> fp16 (into out rows' first 512B) + row ||z||^2 ----------
__global__ __launch_bounds__(256)
void prep_z_kernel(const float* __restrict__ z, char* __restrict__ outb,
                   float* __restrict__ z_sq) {
    const int l = threadIdx.x & 63;
    const int w = threadIdx.x >> 6;
    const int wave = blockIdx.x * 4 + w;
#pragma unroll 4
    for (int i = 0; i < 16; ++i) {
        int row = wave * 16 + i;
        float4 v = ((const float4*)(z + (size_t)row * DIM))[l];
        float ss = v.x * v.x + v.y * v.y + v.z * v.z + v.w * v.w;
        h4 hv = { (_Float16)v.x, (_Float16)v.y, (_Float16)v.z, (_Float16)v.w };
        *(h4*)(outb + (size_t)row * 1024 + l * 8) = hv;
#pragma unroll
        for (int off = 32; off > 0; off >>= 1) ss += __shfl_down(ss, off);
        if (l == 0) z_sq[row] = ss;
    }
}

// ---------- prep_cb: codebook fp32 -> fp16 scaled x1024 + e_sq ----------
__global__ __launch_bounds__(256)
void prep_cb_kernel(const float* __restrict__ cb, char* __restrict__ f_hi,
                    float* __restrict__ esq) {
    const int l = threadIdx.x & 63;
    const int w = threadIdx.x >> 6;
    const int code = blockIdx.x * 4 + w;
    float4 v = ((const float4*)(cb + (size_t)code * DIM))[l];
    float ss = v.x * v.x + v.y * v.y + v.z * v.z + v.w * v.w;
    h4 hv = { (_Float16)(v.x * 1024.f), (_Float16)(v.y * 1024.f),
              (_Float16)(v.z * 1024.f), (_Float16)(v.w * 1024.f) };
    *(h4*)(f_hi + (size_t)code * 512 + l * 8) = hv;
#pragma unroll
    for (int off = 32; off > 0; off >>= 1) ss += __shfl_down(ss, off);
    if (l == 0) esq[code] = ss;
}

// ---------- main: f16 MFMA distances + packed top-2 argmin + fused out/loss/hist ----------
__global__ __launch_bounds__(256, 4)
void gemm_argmin_kernel(const char* __restrict__ zhib,   // z_hi strided 1024B/row (in out buf)
                        const char* __restrict__ f_hi,   // fp16 codebook x1024, 512B/row
                        const float* __restrict__ esq,
                        const float* __restrict__ z_sq,
                        const float* __restrict__ cb,    // fp32 codebook (for gather)
                        float* __restrict__ out,
                        int* __restrict__ hist, float* __restrict__ loss_sum,
                        int* __restrict__ cnt, Flag* __restrict__ flags) {
    __shared__ __align__(16) char arena[40960];  // [0,8K) zL  [8K,40K) cL
    const int tid = threadIdx.x;
    const int w = tid >> 6;
    const int l = tid & 63;
    const int l15 = l & 15;
    const int lhi = l >> 4;
    const int b0 = blockIdx.x * BM;

    const h8* zLh = (const h8*)(arena);
    const h8* cLh = (const h8*)(arena + 8192);

    float top_b[4], top_s[4];
#pragma unroll
    for (int i = 0; i < 4; ++i) { top_b[i] = INFINITY; top_s[i] = INFINITY; }

    for (int cc = 0; cc < NCC; ++cc) {
        f32x4 acc[4][4];   // [fc][fz]
#pragma unroll
        for (int i = 0; i < 4; ++i)
#pragma unroll
            for (int j = 0; j < 4; ++j) acc[i][j] = (f32x4){0.f, 0.f, 0.f, 0.f};

        for (int kc = 0; kc < NKC; ++kc) {
            __syncthreads();
            // stage z tile: 8KB, wave w -> chunks 2w,2w+1 (1KB each)
#pragma unroll
            for (int q = 0; q < 2; ++q) {
                int ch = w * 2 + q;
                int row = ch * 8 + (l >> 3);
                const char* src = zhib + (size_t)(b0 + row) * 1024 + kc * 128 + (l & 7) * 16;
                gl_lds16(arena + ch * 1024, src);
            }
            // stage cb tile: 32KB, wave w -> chunks 8w..8w+7
#pragma unroll
            for (int q = 0; q < 8; ++q) {
                int ch = w * 8 + q;
                int crow = ch * 8 + (l >> 3);
                const char* src = f_hi + (size_t)(cc * CCH + crow) * 512 + kc * 128 + (l & 7) * 16;
                gl_lds16(arena + 8192 + ch * 1024, src);
            }
            __syncthreads();   // compiler drains vmcnt(0) before s_barrier (m97 pattern)

#pragma unroll
            for (int s = 0; s < 2; ++s) {
                h8 bfr[4];
#pragma unroll
                for (int fz = 0; fz < 4; ++fz)
                    bfr[fz] = zLh[(fz * 16 + l15) * 8 + s * 4 + lhi];
#pragma unroll
                for (int fc = 0; fc < 4; ++fc) {
                    h8 afr = cLh[(w * 64 + fc * 16 + l15) * 8 + s * 4 + lhi];
#pragma unroll
                    for (int fz = 0; fz < 4; ++fz)
                        acc[fc][fz] = __builtin_amdgcn_mfma_f32_16x16x32_f16(
                            afr, bfr[fz], acc[fc][fz], 0, 0, 0);
                }
            }
        }
        // epilogue: dist = esq - acc/512 ; packed top-2 (idx in low 10 mantissa bits)
#pragma unroll
        for (int fc = 0; fc < 4; ++fc) {
#pragma unroll
            for (int r = 0; r < 4; ++r) {
                int code = cc * CCH + w * 64 + fc * 16 + lhi * 4 + r;
                float es = esq[code];
#pragma unroll
                for (int fz = 0; fz < 4; ++fz) {
                    float dist = fmaf(acc[fc][fz][r], -0.001953125f, es);
                    float p = __uint_as_float((__float_as_uint(dist) & ~1023u) | (unsigned)code);
                    top_s[fz] = fminf(top_s[fz], fmaxf(top_b[fz], p));
                    top_b[fz] = fminf(top_b[fz], p);
                }
            }
        }
    }

    // cross-wave top-2 reduce
    __syncthreads();
#pragma unroll
    for (int fz = 0; fz < 4; ++fz) {
        int row = fz * 16 + l15;
        int entry = w * 4 + lhi;
        *(float2*)(arena + row * 128 + entry * 8) = make_float2(top_b[fz], top_s[fz]);
    }
    __syncthreads();
    int* bidx = (int*)(arena + 8192);
    if (tid < BM) {
        float b = INFINITY, s2 = INFINITY;
#pragma unroll
        for (int e = 0; e < 16; ++e) {
            float2 v = *(float2*)(arena + tid * 128 + e * 8);
            s2 = fminf(fminf(s2, v.y), fmaxf(b, v.x));
            b = fminf(b, v.x);
        }
        unsigned ib = __float_as_uint(b) & 1023u;
        bidx[tid] = (int)ib;
        atomicAdd(&hist[ib], 1);
        float lr = z_sq[b0 + tid] + b;
#pragma unroll
        for (int off = 32; off > 0; off >>= 1) lr += __shfl_down(lr, off);
        if (tid == 0) atomicAdd(loss_sum, lr);
        if (s2 - b < FLAG_GAP) {
            int pos = atomicAdd(cnt, 1);
            if (pos < FLAG_CAP) {
                flags[pos].row = b0 + tid;
                flags[pos].i1 = (int)ib;
                flags[pos].i2 = (int)(__float_as_uint(s2) & 1023u);
            }
        }
    }
    __syncthreads();
    // gather chosen codebook rows -> out (4 threads per row, 64B chunks)
    {
        int row = tid >> 2, q = tid & 3;
        int ib = bidx[row];
        const float4* src = (const float4*)(cb + (size_t)ib * DIM + q * 64);
        float4* dst = (float4*)(out + (size_t)(b0 + row) * DIM + q * 64);
#pragma unroll
        for (int i = 0; i < 16; ++i) dst[i] = src[i];
    }
}

// ---------- rescue: fp64 rescoring of near-tie rows; fix out/hist/loss ----------
__global__ __launch_bounds__(256)
void rescue_kernel(const float* __restrict__ z, const float* __restrict__ cb,
                   const int* __restrict__ cnt, const Flag* __restrict__ flags,
                   float* __restrict__ out, int* __restrict__ hist,
                   float* __restrict__ loss_sum) {
    int n = *cnt; if (n > FLAG_CAP) n = FLAG_CAP;
    const int l = threadIdx.x & 63;
    const int wave = (blockIdx.x * blockDim.x + threadIdx.x) >> 6;
    const int nw = (gridDim.x * blockDim.x) >> 6;
    for (int f = wave; f < n; f += nw) {
        Flag fl = flags[f];
        float4 zv = ((const float4*)(z + (size_t)fl.row * DIM))[l];
        float4 a = ((const float4*)(cb + (size_t)fl.i1 * DIM))[l];
        float4 b = ((const float4*)(cb + (size_t)fl.i2 * DIM))[l];
        double s1 = (double)a.x * (a.x - 2.0 * zv.x) + (double)a.y * (a.y - 2.0 * zv.y)
                  + (double)a.z * (a.z - 2.0 * zv.z) + (double)a.w * (a.w - 2.0 * zv.w);
        double s2 = (double)b.x * (b.x - 2.0 * zv.x) + (double)b.y * (b.y - 2.0 * zv.y)
                  + (double)b.z * (b.z - 2.0 * zv.z) + (double)b.w * (b.w - 2.0 * zv.w);
#pragma unroll
        for (int off = 32; off > 0; off >>= 1) {
            s1 += __shfl_down(s1, off);
            s2 += __shfl_down(s2, off);
        }
        s1 = __shfl(s1, 0);
        s2 = __shfl(s2, 0);
        int win2 = (s2 < s1) || (s2 == s1 && fl.i2 < fl.i1);
        if (win2) {
            ((float4*)(out + (size_t)fl.row * DIM))[l] = b;
            if (l == 0) {
                atomicAdd(&hist[fl.i2], 1);
                atomicAdd(&hist[fl.i1], -1);
                atomicAdd(loss_sum, (float)(s2 - s1));
            }
        }
    }
}

// ---------- final: perplexity + vq_loss ----------
__global__ __launch_bounds__(256)
void vq_final_kernel(const int* __restrict__ hist, const float* __restrict__ loss_sum,
                     float* __restrict__ out) {
    int tid = threadIdx.x;
    float s = 0.f;
    for (int t = tid; t < NCODES; t += 256) {
        float p = (float)hist[t] * (1.0f / 65536.f);
        s += p * logf(p + 1e-10f);
    }
#pragma unroll
    for (int off = 32; off > 0; off >>= 1) s += __shfl_down(s, off);
    __shared__ float wsum[4];
    if ((tid & 63) == 0) wsum[tid >> 6] = s;
    __syncthreads();
    if (tid == 0) {
        float tot = wsum[0] + wsum[1] + wsum[2] + wsum[3];
        float perp = expf(-tot);
        float mse = loss_sum[0] * (1.0f / 16777216.f);
        float ratio = 102.4f / (perp + 1e-10f);
        ratio = fminf(fmaxf(ratio, 0.f), 10.f);
        out[(size_t)NROWS * DIM] = 1.25f * mse + 0.1f * ratio;
        out[(size_t)NROWS * DIM + 1] = perp;
    }
}

extern "C" void kernel_launch(void* const* d_in, const int* in_sizes, int n_in,
                              void* d_out, int out_size, void* d_ws, size_t ws_size,
                              hipStream_t stream) {
    const float* z = (const float*)d_in[0];
    const float* cb = (const float*)d_in[1];
    float* out = (float*)d_out;
    char* ws = (char*)d_ws;

    // ws layout (kept within round-1-proven 897KB footprint)
    int*   hist  = (int*)(ws + 0);        // 4096
    float* loss  = (float*)(ws + 4096);   // 4
    int*   cnt   = (int*)(ws + 4100);     // 4
    float* esq   = (float*)(ws + 8192);   // 4096
    float* z_sq  = (float*)(ws + 12288);  // 262144
    Flag*  flags = (Flag*)(ws + 274432);  // 98304
    char*  f_hi  = ws + 372736;           // 524288

    hipMemsetAsync(ws, 0, 4104, stream);  // hist + loss + cnt
    prep_z_kernel<<<1024, 256, 0, stream>>>(z, (char*)d_out, z_sq);
    prep_cb_kernel<<<256, 256, 0, stream>>>(cb, f_hi, esq);
    gemm_argmin_kernel<<<NROWS / BM, 256, 0, stream>>>(
        (const char*)d_out, f_hi, esq, z_sq, cb, out, hist, loss, cnt, flags);
    rescue_kernel<<<32, 256, 0, stream>>>(z, cb, cnt, flags, out, hist, loss);
    vq_final_kernel<<<1, 256, 0, stream>>>(hist, loss, out);
}

// Round 6
// 260.376 us; speedup vs baseline: 2.2197x; 1.0222x over previous
//
#include <hip/hip_runtime.h>
#include <math.h>

#define NROWS 65536
#define NCODES 1024
#define DIM 256
#define BM 128              // z-rows per block (4 waves x 32 rows)
#define TCODES 64           // codes per LDS tile
#define NTILES 16           // NCODES / TCODES
#define FLAG_CAP 8192
#define FLAG_GAP 3e-4f

typedef _Float16 h8 __attribute__((ext_vector_type(8)));
typedef _Float16 h4 __attribute__((ext_vector_type(4)));
typedef float f32x4 __attribute__((ext_vector_type(4)));

struct Flag { int row; int i1; int i2; };

__device__ __forceinline__ void gl_lds16(void* lds, const void* g) {
    __builtin_amdgcn_global_load_lds(
        (const __attribute__((address_space(1))) unsigned int*)g,
        (__attribute__((address_space(3))) unsigned int*)lds, 16, 0, 0);
}

// ---------- prep_z: z fp32 -> fp16 swizzled (into out rows' first 512B) + row ||z||^2 ----------
__global__ __launch_bounds__(256)
void prep_z_kernel(const float* __restrict__ z, char* __restrict__ outb,
                   float* __restrict__ z_sq) {
    const int l = threadIdx.x & 63;
    const int w = threadIdx.x >> 6;
    const int wave = blockIdx.x * 4 + w;
#pragma unroll 4
    for (int i = 0; i < 16; ++i) {
        int row = wave * 16 + i;
        float4 v = ((const float4*)(z + (size_t)row * DIM))[l];
        float ss = v.x * v.x + v.y * v.y + v.z * v.z + v.w * v.w;
        h4 hv = { (_Float16)v.x, (_Float16)v.y, (_Float16)v.z, (_Float16)v.w };
        int col = (l * 8) ^ ((row & 7) << 4);          // XOR swizzle (read undoes it)
        *(h4*)(outb + (size_t)row * 1024 + col) = hv;
#pragma unroll
        for (int off = 32; off > 0; off >>= 1) ss += __shfl_down(ss, off);
        if (l == 0) z_sq[row] = ss;
    }
}

// ---------- prep_cb: codebook fp32 -> fp16 x1024 swizzled + e_sq ----------
__global__ __launch_bounds__(256)
void prep_cb_kernel(const float* __restrict__ cb, char* __restrict__ f_hi,
                    float* __restrict__ esq) {
    const int l = threadIdx.x & 63;
    const int w = threadIdx.x >> 6;
    const int code = blockIdx.x * 4 + w;
    float4 v = ((const float4*)(cb + (size_t)code * DIM))[l];
    float ss = v.x * v.x + v.y * v.y + v.z * v.z + v.w * v.w;
    h4 hv = { (_Float16)(v.x * 1024.f), (_Float16)(v.y * 1024.f),
              (_Float16)(v.z * 1024.f), (_Float16)(v.w * 1024.f) };
    int col = (l * 8) ^ ((code & 7) << 4);
    *(h4*)(f_hi + (size_t)code * 512 + col) = hv;
#pragma unroll
    for (int off = 32; off > 0; off >>= 1) ss += __shfl_down(ss, off);
    if (l == 0) esq[code] = ss;
}

// ---------- main: z-in-regs, cb double-buffered, counted-vmcnt pipeline ----------
#define STAGE(bo, tile) do {                                                   \
    _Pragma("unroll")                                                          \
    for (int i_ = 0; i_ < 8; ++i_)                                             \
        gl_lds16(arena + (bo) + i_ * 4096 + tid * 16,                          \
                 f_hi + (size_t)(tile) * 32768 + i_ * 4096 + tid * 16);        \
} while (0)

__global__ __launch_bounds__(256, 2)
void gemm_argmin_kernel(const char* __restrict__ zhib,   // fp16 z, swizzled, 1024B/row (in out buf)
                        const char* __restrict__ f_hi,   // fp16 cb x1024, swizzled, 512B/row
                        const float* __restrict__ esq_g,
                        const float* __restrict__ z_sq,
                        const float* __restrict__ cb,    // fp32 codebook (gather)
                        float* __restrict__ out,
                        int* __restrict__ hist, float* __restrict__ loss_sum,
                        int* __restrict__ cnt, Flag* __restrict__ flags) {
    // [0,64K) cb double-buffer (z staging in prologue) | [64K,68K) esq | [68K,+512) bidx
    __shared__ __align__(16) char arena[70144];
    const int tid = threadIdx.x;
    const int w = tid >> 6;
    const int l = tid & 63;
    const int l15 = l & 15;
    const int lhi = l >> 4;
    const int b0 = blockIdx.x * BM;

    // ---- prologue: stage esq (4KB) + this block's z (64KB) into LDS ----
    gl_lds16(arena + 65536 + tid * 16, esq_g + tid * 4);
#pragma unroll
    for (int i = 0; i < 16; ++i) {
        int L = i * 4096 + tid * 16;
        gl_lds16(arena + L, zhib + (size_t)(b0 + (L >> 9)) * 1024 + (L & 511));
    }
    __syncthreads();

    // z fragments -> registers (64 VGPR); wave w owns rows w*32..w*32+31
    h8 zf0[8], zf1[8];
#pragma unroll
    for (int s = 0; s < 8; ++s) {
        const int r0 = w * 32 + l15;
        const int r1 = w * 32 + 16 + l15;
        zf0[s] = *(const h8*)(arena + r0 * 512 + ((64 * s + 16 * lhi) ^ ((r0 & 7) << 4)));
        zf1[s] = *(const h8*)(arena + r1 * 512 + ((64 * s + 16 * lhi) ^ ((r1 & 7) << 4)));
    }
    __syncthreads();   // all waves done reading z before cb staging overwrites

    const float* esqL = (const float*)(arena + 65536);
    float topb0 = INFINITY, tops0 = INFINITY, topb1 = INFINITY, tops1 = INFINITY;

    STAGE(0, 0);
    STAGE(32768, 1);   // 16 loads/thread outstanding

    for (int t = 0; t < NTILES; ++t) {
        const int bo = (t & 1) << 15;
        if (t == NTILES - 1) { asm volatile("s_waitcnt vmcnt(0)" ::: "memory"); }
        else                 { asm volatile("s_waitcnt vmcnt(8)" ::: "memory"); }
        __builtin_amdgcn_s_barrier();

        f32x4 acc[4][2];
#pragma unroll
        for (int fc = 0; fc < 4; ++fc) {
            acc[fc][0] = (f32x4){0.f, 0.f, 0.f, 0.f};
            acc[fc][1] = (f32x4){0.f, 0.f, 0.f, 0.f};
        }
#pragma unroll
        for (int s = 0; s < 8; ++s) {
#pragma unroll
            for (int fc = 0; fc < 4; ++fc) {
                const int cl = fc * 16 + l15;
                h8 afr = *(const h8*)(arena + bo + cl * 512 +
                                      ((64 * s + 16 * lhi) ^ ((cl & 7) << 4)));
                acc[fc][0] = __builtin_amdgcn_mfma_f32_16x16x32_f16(afr, zf0[s], acc[fc][0], 0, 0, 0);
                acc[fc][1] = __builtin_amdgcn_mfma_f32_16x16x32_f16(afr, zf1[s], acc[fc][1], 0, 0, 0);
            }
        }
        __builtin_amdgcn_sched_barrier(0);   // pin ds_reads above the buffer-recycle barrier
        __builtin_amdgcn_s_barrier();
        if (t < NTILES - 2) STAGE(bo, t + 2);

        // top-2 epilogue (register-only; overlaps staging)
#pragma unroll
        for (int fc = 0; fc < 4; ++fc) {
#pragma unroll
            for (int r = 0; r < 4; ++r) {
                const int code = t * 64 + fc * 16 + lhi * 4 + r;
                const float es = esqL[code];
                float d0 = fmaf(acc[fc][0][r], -0.001953125f, es);
                float d1 = fmaf(acc[fc][1][r], -0.001953125f, es);
                float p0 = __uint_as_float((__float_as_uint(d0) & ~1023u) | (unsigned)code);
                float p1 = __uint_as_float((__float_as_uint(d1) & ~1023u) | (unsigned)code);
                tops0 = fminf(tops0, fmaxf(topb0, p0));
                topb0 = fminf(topb0, p0);
                tops1 = fminf(tops1, fmaxf(topb1, p1));
                topb1 = fminf(topb1, p1);
            }
        }
    }

    // merge top-2 across the 4 lhi groups (lanes l ^ 16, l ^ 32)
#pragma unroll
    for (int m = 16; m <= 32; m <<= 1) {
        float ob = __shfl_xor(topb0, m, 64), os = __shfl_xor(tops0, m, 64);
        tops0 = fminf(fminf(tops0, os), fmaxf(topb0, ob));
        topb0 = fminf(topb0, ob);
        ob = __shfl_xor(topb1, m, 64); os = __shfl_xor(tops1, m, 64);
        tops1 = fminf(fminf(tops1, os), fmaxf(topb1, ob));
        topb1 = fminf(topb1, ob);
    }

    int* bidx = (int*)(arena + 69632);
    float lr = 0.f;
    if (lhi == 0) {
#pragma unroll
        for (int fz = 0; fz < 2; ++fz) {
            const float b = fz ? topb1 : topb0;
            const float s2 = fz ? tops1 : tops0;
            const int row = w * 32 + fz * 16 + l15;
            const unsigned ib = __float_as_uint(b) & 1023u;
            bidx[row] = (int)ib;
            atomicAdd(&hist[ib], 1);
            lr += z_sq[b0 + row] + __uint_as_float(__float_as_uint(b) & ~1023u);
            if (s2 - b < FLAG_GAP) {
                int pos = atomicAdd(cnt, 1);
                if (pos < FLAG_CAP) {
                    flags[pos].row = b0 + row;
                    flags[pos].i1 = (int)ib;
                    flags[pos].i2 = (int)(__float_as_uint(s2) & 1023u);
                }
            }
        }
    }
#pragma unroll
    for (int off = 32; off > 0; off >>= 1) lr += __shfl_down(lr, off, 64);
    if (l == 0) atomicAdd(loss_sum, lr);

    __syncthreads();
    // gather chosen codebook rows -> out (2 threads per row, 512B each)
    {
        const int row = tid >> 1, q = tid & 1;
        const int ib = bidx[row];
        const float4* src = (const float4*)(cb + (size_t)ib * DIM + q * 128);
        float4* dst = (float4*)(out + (size_t)(b0 + row) * DIM + q * 128);
#pragma unroll
        for (int i = 0; i < 32; ++i) dst[i] = src[i];
    }
}

// ---------- rescue: fp64 rescoring of near-tie rows; fix out/hist/loss ----------
__global__ __launch_bounds__(256)
void rescue_kernel(const float* __restrict__ z, const float* __restrict__ cb,
                   const int* __restrict__ cnt, const Flag* __restrict__ flags,
                   float* __restrict__ out, int* __restrict__ hist,
                   float* __restrict__ loss_sum) {
    int n = *cnt; if (n > FLAG_CAP) n = FLAG_CAP;
    const int l = threadIdx.x & 63;
    const int wave = (blockIdx.x * blockDim.x + threadIdx.x) >> 6;
    const int nw = (gridDim.x * blockDim.x) >> 6;
    for (int f = wave; f < n; f += nw) {
        Flag fl = flags[f];
        float4 zv = ((const float4*)(z + (size_t)fl.row * DIM))[l];
        float4 a = ((const float4*)(cb + (size_t)fl.i1 * DIM))[l];
        float4 b = ((const float4*)(cb + (size_t)fl.i2 * DIM))[l];
        double s1 = (double)a.x * (a.x - 2.0 * zv.x) + (double)a.y * (a.y - 2.0 * zv.y)
                  + (double)a.z * (a.z - 2.0 * zv.z) + (double)a.w * (a.w - 2.0 * zv.w);
        double s2 = (double)b.x * (b.x - 2.0 * zv.x) + (double)b.y * (b.y - 2.0 * zv.y)
                  + (double)b.z * (b.z - 2.0 * zv.z) + (double)b.w * (b.w - 2.0 * zv.w);
#pragma unroll
        for (int off = 32; off > 0; off >>= 1) {
            s1 += __shfl_down(s1, off);
            s2 += __shfl_down(s2, off);
        }
        s1 = __shfl(s1, 0);
        s2 = __shfl(s2, 0);
        int win2 = (s2 < s1) || (s2 == s1 && fl.i2 < fl.i1);
        if (win2) {
            ((float4*)(out + (size_t)fl.row * DIM))[l] = b;
            if (l == 0) {
                atomicAdd(&hist[fl.i2], 1);
                atomicAdd(&hist[fl.i1], -1);
                atomicAdd(loss_sum, (float)(s2 - s1));
            }
        }
    }
}

// ---------- final: perplexity + vq_loss ----------
__global__ __launch_bounds__(256)
void vq_final_kernel(const int* __restrict__ hist, const float* __restrict__ loss_sum,
                     float* __restrict__ out) {
    int tid = threadIdx.x;
    float s = 0.f;
    for (int t = tid; t < NCODES; t += 256) {
        float p = (float)hist[t] * (1.0f / 65536.f);
        s += p * logf(p + 1e-10f);
    }
#pragma unroll
    for (int off = 32; off > 0; off >>= 1) s += __shfl_down(s, off);
    __shared__ float wsum[4];
    if ((tid & 63) == 0) wsum[tid >> 6] = s;
    __syncthreads();
    if (tid == 0) {
        float tot = wsum[0] + wsum[1] + wsum[2] + wsum[3];
        float perp = expf(-tot);
        float mse = loss_sum[0] * (1.0f / 16777216.f);
        float ratio = 102.4f / (perp + 1e-10f);
        ratio = fminf(fmaxf(ratio, 0.f), 10.f);
        out[(size_t)NROWS * DIM] = 1.25f * mse + 0.1f * ratio;
        out[(size_t)NROWS * DIM + 1] = perp;
    }
}

extern "C" void kernel_launch(void* const* d_in, const int* in_sizes, int n_in,
                              void* d_out, int out_size, void* d_ws, size_t ws_size,
                              hipStream_t stream) {
    const float* z = (const float*)d_in[0];
    const float* cb = (const float*)d_in[1];
    float* out = (float*)d_out;
    char* ws = (char*)d_ws;

    int*   hist  = (int*)(ws + 0);        // 4096
    float* loss  = (float*)(ws + 4096);   // 4
    int*   cnt   = (int*)(ws + 4100);     // 4
    float* esq   = (float*)(ws + 8192);   // 4096
    float* z_sq  = (float*)(ws + 12288);  // 262144
    Flag*  flags = (Flag*)(ws + 274432);  // 98304
    char*  f_hi  = ws + 372736;           // 524288

    hipMemsetAsync(ws, 0, 4104, stream);  // hist + loss + cnt
    prep_z_kernel<<<1024, 256, 0, stream>>>(z, (char*)d_out, z_sq);
    prep_cb_kernel<<<256, 256, 0, stream>>>(cb, f_hi, esq);
    gemm_argmin_kernel<<<NROWS / BM, 256, 0, stream>>>(
        (const char*)d_out, f_hi, esq, z_sq, cb, out, hist, loss, cnt, flags);
    rescue_kernel<<<32, 256, 0, stream>>>(z, cb, cnt, flags, out, hist, loss);
    vq_final_kernel<<<1, 256, 0, stream>>>(hist, loss, out);
}